// Round 12
// baseline (259.443 us; speedup 1.0000x reference)
//
#include <hip/hip_runtime.h>
#include <math.h>

// ---------------------------------------------------------------------------
// GraphTransformerBlock: TransformerConv (4 heads x 32) + residual MLP.
// Round 12: EA permuted to CSR order as bf16 in scatter (EAP, 64B rows).
// Gather's edge-attr reads become streaming + half-width; SE int2 -> srcs int.
// Gather keeps the round-11 4-deep pipeline. Everything else unchanged.
// ---------------------------------------------------------------------------

#define D 128
#define EDIM 32

using bf16x8 = __attribute__((ext_vector_type(8))) short;
using f32x4  = __attribute__((ext_vector_type(4))) float;
using ushort8 = __attribute__((ext_vector_type(8))) unsigned short;

__device__ inline unsigned short f2bf(float f) {
    unsigned int u = __float_as_uint(f);
    u += 0x7FFFu + ((u >> 16) & 1u);          // round-to-nearest-even
    return (unsigned short)(u >> 16);
}
__device__ inline float bf2f(unsigned short h) {
    return __uint_as_float(((unsigned int)h) << 16);
}
__device__ inline float gelu_fast(float x) {
    float x3 = x * x * x;
    float u = 0.7978845608028654f * (x + 0.044715f * x3);
    float t = 1.f - 2.f / (__expf(2.f * u) + 1.f);   // tanh(u)
    return 0.5f * x * (1.f + t);
}
// sum over aligned 4-lane quad via DPP quad_perm (all 4 lanes get the sum)
__device__ inline float quad_add(float x) {
    int a = __builtin_amdgcn_update_dpp(0, __float_as_int(x), 0xB1, 0xF, 0xF, true);
    x += __int_as_float(a);
    a = __builtin_amdgcn_update_dpp(0, __float_as_int(x), 0x4E, 0xF, 0xF, true);
    x += __int_as_float(a);
    return x;
}

// swizzled B-frag read: element (col, kk0..kk0+7) of the staged weight tile
__device__ inline bf16x8 ldsB(const unsigned short* sw, int col, int kk0) {
    return *(const bf16x8*)(sw + col * 128 + (kk0 ^ ((col & 7) << 3)));
}

// ---------------------------------------------------------------------------
// prep: blocks 0..511 -> 8 pre-swizzled bf16 weight tables
//   Wt[m][col*128 + (kk ^ ((col&7)<<3))] = W_m[kk][col]
//   m: 0=Wq 1=Wk 2=Wv 3=Wskip 4=W1 5=W2 6=WqE (inline dot) 7=WtCorr
// block 512: bqE.  blocks 513..513+HB-1: hist. blocks 513+HB..: x -> bf16.
// ---------------------------------------------------------------------------
__global__ __launch_bounds__(256) void prep_kernel(
    const float* __restrict__ Wq, const float* __restrict__ Wk,
    const float* __restrict__ Wv, const float* __restrict__ Wsk,
    const float* __restrict__ W1, const float* __restrict__ W2,
    const float* __restrict__ We, const float* __restrict__ bq,
    unsigned short* __restrict__ Wt, float* __restrict__ bqE,
    const int* __restrict__ EI, int* __restrict__ deg, int E, int HB,
    const float* __restrict__ x, unsigned short* __restrict__ XB, long xtot)
{
    if ((int)blockIdx.x >= 513 + HB) {    // x -> bf16 tail
        long i8 = ((long)(blockIdx.x - 513 - HB) * 256 + threadIdx.x) * 8;
        if (i8 + 8 <= xtot) {
            float4 a = *(const float4*)(x + i8);
            float4 b = *(const float4*)(x + i8 + 4);
            ushort8 u;
            u[0] = f2bf(a.x); u[1] = f2bf(a.y); u[2] = f2bf(a.z); u[3] = f2bf(a.w);
            u[4] = f2bf(b.x); u[5] = f2bf(b.y); u[6] = f2bf(b.z); u[7] = f2bf(b.w);
            *(ushort8*)(XB + i8) = u;
        }
        return;
    }
    if (blockIdx.x >= 513) {              // hist
        int e = (blockIdx.x - 513) * 256 + threadIdx.x;
        if (e < E) atomicAdd(&deg[EI[E + e]], 1);
        return;
    }
    int t = blockIdx.x * 256 + threadIdx.x;
    int m = t >> 14;
    int r = t & 16383;
    if (m >= 8) {                         // bqE block
        if (r < 128) {
            const int hb = r & 96, k = r & 31;
            const float* wek = We + (size_t)k * D + hb;
            float s = 0.f;
#pragma unroll 8
            for (int c = 0; c < 32; ++c) s = fmaf(bq[hb + c], wek[c], s);
            bqE[r] = s;
        }
        return;
    }
    int col = r & 127, kk = r >> 7;
    float v;
    if (m < 6) {
        const float* W = (m == 0) ? Wq : (m == 1) ? Wk : (m == 2) ? Wv
                       : (m == 3) ? Wsk : (m == 4) ? W1 : W2;
        v = W[(size_t)kk * D + col];
    } else if (m == 6) {
        const int hb = col & 96;
        const float* wqr = Wq + (size_t)kk * D + hb;
        const float* wer = We + (size_t)(col & 31) * D + hb;
        float s = 0.f;
#pragma unroll 8
        for (int c = 0; c < 32; ++c) s = fmaf(wqr[c], wer[c], s);
        v = s;
    } else {
        v = ((kk >> 5) == (col >> 5)) ? We[(size_t)(kk & 31) * D + col] : 0.f;
    }
    Wt[(size_t)m * 16384 + (size_t)col * 128 + (kk ^ ((col & 7) << 3))] = f2bf(v);
}

// ---------------------------------------------------------------------------
// hierarchical scan
// ---------------------------------------------------------------------------
__global__ __launch_bounds__(1024) void scanA(
    const int* __restrict__ deg, int* __restrict__ rowptr,
    int* __restrict__ psums, int N)
{
    __shared__ int tmp[1024];
    const int t = threadIdx.x;
    const int i = blockIdx.x * 1024 + t;
    int v = (i < N) ? deg[i] : 0;
    tmp[t] = v;
    __syncthreads();
    for (int off = 1; off < 1024; off <<= 1) {
        int add = (t >= off) ? tmp[t - off] : 0;
        __syncthreads();
        tmp[t] += add;
        __syncthreads();
    }
    if (i < N) rowptr[i + 1] = tmp[t];
    if (t == 1023) psums[blockIdx.x] = tmp[1023];
}

__global__ __launch_bounds__(1024) void scanB(int* __restrict__ psums, int nb)
{
    __shared__ int tmp[1024];
    const int t = threadIdx.x;
    int v = (t < nb) ? psums[t] : 0;
    tmp[t] = v;
    __syncthreads();
    for (int off = 1; off < 1024; off <<= 1) {
        int add = (t >= off) ? tmp[t - off] : 0;
        __syncthreads();
        tmp[t] += add;
        __syncthreads();
    }
    if (t < nb) psums[t] = tmp[t] - v;   // exclusive
}

__global__ __launch_bounds__(256) void scanC(
    int* __restrict__ rowptr, int* __restrict__ cursor,
    const int* __restrict__ psums, int N)
{
    int i = blockIdx.x * 256 + threadIdx.x;
    if (i == 0) { rowptr[0] = 0; cursor[0] = 0; }
    if (i < N) {
        int val = rowptr[i + 1] + psums[i >> 10];
        rowptr[i + 1] = val;
        if (i + 1 < N) cursor[i + 1] = val;
    }
}

// ---------------------------------------------------------------------------
// scatter: srcs[pos]=src + EAP[pos]=bf16(edge_attr[e]) (CSR-ordered, 64B row).
// EA read is streaming; EAP/srcs writes are scattered full/partial sectors
// (fire-and-forget; no latency stall).
// ---------------------------------------------------------------------------
__global__ __launch_bounds__(256) void scatter_kernel(
    const int* __restrict__ EI, const float* __restrict__ EA,
    int* __restrict__ cursor, int* __restrict__ srcs,
    unsigned short* __restrict__ EAP, int E)
{
    int e = blockIdx.x * 256 + threadIdx.x;
    if (e >= E) return;
    int dst = EI[E + e];
    int pos = atomicAdd(&cursor[dst], 1);
    srcs[pos] = EI[e];
    const float4* s4 = (const float4*)(EA + (size_t)e * EDIM);
    unsigned short* op = EAP + (size_t)pos * EDIM;
#pragma unroll
    for (int j = 0; j < 4; ++j) {
        float4 a = s4[2 * j], b = s4[2 * j + 1];
        ushort8 u;
        u[0] = f2bf(a.x); u[1] = f2bf(a.y); u[2] = f2bf(a.z); u[3] = f2bf(a.w);
        u[4] = f2bf(b.x); u[5] = f2bf(b.y); u[6] = f2bf(b.z); u[7] = f2bf(b.w);
        *(ushort8*)(op + j * 8) = u;
    }
}

// ---------------------------------------------------------------------------
// gemm5: blockIdx.x = m*NB2 + bx, m=0..4 (Q,K,V,skip,QE). 128-row tiles.
// bf16 outputs (m!=3) are transposed through LDS (re-using sw) so global
// stores are full-line ushort8; skip (m==3) stores f32 directly.
// ---------------------------------------------------------------------------
__global__ __launch_bounds__(256) void gemm5(
    const unsigned short* __restrict__ XB, const unsigned short* __restrict__ Wt,
    const float* __restrict__ bq, const float* __restrict__ bk,
    const float* __restrict__ bv, const float* __restrict__ bs,
    const float* __restrict__ bqE,
    unsigned short* __restrict__ QA, unsigned short* __restrict__ KV,
    float* __restrict__ S, int N, int NB2)
{
    __shared__ unsigned short sw[16384];
    const int t = threadIdx.x;
    const int bid = blockIdx.x;
    const int m = bid / NB2;
    const int bx = bid - m * NB2;
    const int widx = (m < 4) ? m : 6;
    const int lane = t & 63;
    const int w = t >> 6;
    const int row0 = bx * 128 + w * 32;
    const int lrow = lane & 15;
    const int kb = (lane >> 4) * 8;
    const int rq = (lane >> 4) * 4;

    const unsigned short* gsrc = Wt + (size_t)widx * 16384;
    ushort8 stg[8];
#pragma unroll
    for (int it = 0; it < 8; ++it)
        stg[it] = *(const ushort8*)(gsrc + (t + it * 256) * 8);

    bf16x8 af0[4], af1[4];
    {
        int a0 = row0 + lrow;      if (a0 > N - 1) a0 = N - 1;
        int a1 = row0 + 16 + lrow; if (a1 > N - 1) a1 = N - 1;
        const unsigned short* x0 = XB + (size_t)a0 * D + kb;
        const unsigned short* x1 = XB + (size_t)a1 * D + kb;
#pragma unroll
        for (int kf = 0; kf < 4; ++kf) {
            af0[kf] = *(const bf16x8*)(x0 + kf * 32);
            af1[kf] = *(const bf16x8*)(x1 + kf * 32);
        }
    }

#pragma unroll
    for (int it = 0; it < 8; ++it)
        *(ushort8*)(&sw[(t + it * 256) * 8]) = stg[it];
    __syncthreads();

    const float* bias = (m == 0) ? bq : (m == 1) ? bk : (m == 2) ? bv
                      : (m == 3) ? bs : bqE;
    f32x4 acc0[8], acc1[8];
#pragma unroll
    for (int nf = 0; nf < 8; ++nf) {
        acc0[nf] = (f32x4){0.f, 0.f, 0.f, 0.f};
        acc1[nf] = (f32x4){0.f, 0.f, 0.f, 0.f};
    }
#pragma unroll
    for (int nf = 0; nf < 8; ++nf) {
        const int col = nf * 16 + lrow;
#pragma unroll
        for (int kf = 0; kf < 4; ++kf) {
            bf16x8 bfr = ldsB(sw, col, kf * 32 + kb);
            acc0[nf] = __builtin_amdgcn_mfma_f32_16x16x32_bf16(af0[kf], bfr, acc0[nf], 0, 0, 0);
            acc1[nf] = __builtin_amdgcn_mfma_f32_16x16x32_bf16(af1[kf], bfr, acc1[nf], 0, 0, 0);
        }
    }

    if (m == 3) {
        // f32 skip: direct stores (64B-contiguous per (nf,row) segment)
#pragma unroll
        for (int rb = 0; rb < 2; ++rb) {
#pragma unroll
            for (int nf = 0; nf < 8; ++nf) {
                const int col = nf * 16 + lrow;
                const float bb = bias[col];
#pragma unroll
                for (int i = 0; i < 4; ++i) {
                    int r = row0 + rb * 16 + rq + i;
                    if (r < N)
                        S[(size_t)r * D + col] = ((rb == 0) ? acc0[nf][i] : acc1[nf][i]) + bb;
                }
            }
        }
        return;
    }

    // bf16 outputs: bounce through sw (barrier: all MFMA sw-reads are done)
    __syncthreads();
#pragma unroll
    for (int rb = 0; rb < 2; ++rb) {
#pragma unroll
        for (int nf = 0; nf < 8; ++nf) {
            const int col = nf * 16 + lrow;
            const float bb = bias[col];
#pragma unroll
            for (int i = 0; i < 4; ++i)
                sw[(w * 32 + rb * 16 + rq + i) * 128 + col] =
                    f2bf(((rb == 0) ? acc0[nf][i] : acc1[nf][i]) + bb);
        }
    }
    // per-wave patch readback (no cross-wave dependency -> no extra barrier)
    unsigned short* gout = (m == 0) ? QA : (m == 1) ? KV
                         : (m == 2) ? KV + 128 : QA + 128;
#pragma unroll
    for (int it = 0; it < 8; ++it) {
        const int gidx = it * 64 + lane;
        const int row_l = gidx >> 4;          // 0..31
        const int chk = gidx & 15;            // 16B chunk within row
        const int r = row0 + row_l;
        ushort8 vv = *(const ushort8*)(&sw[(w * 32 + row_l) * 128 + chk * 8]);
        if (r < N) *(ushort8*)(gout + (size_t)r * 256 + chk * 8) = vv;
    }
}

// ---------------------------------------------------------------------------
// gather: 1 wave per node; 4 edge groups x 16 lanes (lane owns 8 dims),
// 4 edges per group per iteration (16 edges in flight / wave).
// edge_attr read from EAP (bf16, CSR-ordered -> streaming).
// ---------------------------------------------------------------------------
__global__ __launch_bounds__(256) void gather_pass(
    const int* __restrict__ rowptr, const int* __restrict__ srcs,
    const unsigned short* __restrict__ EAP,
    const unsigned short* __restrict__ QA, const unsigned short* __restrict__ KV,
    float* __restrict__ SB, unsigned short* __restrict__ SAS, int N)
{
    const int lane = threadIdx.x & 63;
    const int wid = threadIdx.x >> 6;
    const int n = blockIdx.x * 4 + wid;
    if (n >= N) return;
    const int g = lane & 15;        // dim slice: d = g*8..+8 (head g>>2)
    const int grp = lane >> 4;      // edge group 0..3
    const int eoff = (g & 3) * 8;   // this lane's EAP slice (bf16)

    float q8[8], qe8[8];
    {
        const unsigned short* qa = QA + (size_t)n * 256 + g * 8;
        bf16x8 qb  = *(const bf16x8*)(qa);
        bf16x8 qeb = *(const bf16x8*)(qa + 128);
#pragma unroll
        for (int j = 0; j < 8; ++j) {
            q8[j]  = bf2f((unsigned short)qb[j]);
            qe8[j] = bf2f((unsigned short)qeb[j]);
        }
    }

    float acc[8], sa[8], den = 0.f;
#pragma unroll
    for (int j = 0; j < 8; ++j) { acc[j] = 0.f; sa[j] = 0.f; }

    const int i0 = rowptr[n], i1 = rowptr[n + 1];

    int src[4];
#pragma unroll
    for (int u = 0; u < 4; ++u) {
        int ii = i0 + grp + u * 4;
        src[u] = (ii < i1) ? srcs[ii] : -1;
    }

    for (int base = i0; base < i1; base += 16) {
        // issue all 12 data loads for the 4 in-flight edges
        bf16x8 kS[4], vS[4], eS[4];
#pragma unroll
        for (int u = 0; u < 4; ++u) {
            kS[u] = (bf16x8){0,0,0,0,0,0,0,0};
            vS[u] = kS[u];
            eS[u] = kS[u];
            if (src[u] >= 0) {
                const unsigned short* kv = KV + (size_t)src[u] * 256 + g * 8;
                kS[u] = *(const bf16x8*)(kv);
                vS[u] = *(const bf16x8*)(kv + 128);
                eS[u] = *(const bf16x8*)(EAP + (size_t)(base + grp + u * 4) * EDIM + eoff);
            }
        }
        // prefetch next iteration's src indices
        int srcN[4];
#pragma unroll
        for (int u = 0; u < 4; ++u) {
            int ii = base + 16 + grp + u * 4;
            srcN[u] = (ii < i1) ? srcs[ii] : -1;
        }
        // compute the 4 edges
#pragma unroll
        for (int u = 0; u < 4; ++u) {
            float ef[8];
            float p = 0.f;
#pragma unroll
            for (int j = 0; j < 8; ++j) {
                ef[j] = bf2f((unsigned short)eS[u][j]);
                p = fmaf(q8[j], bf2f((unsigned short)kS[u][j]),
                         fmaf(ef[j], qe8[j], p));
            }
            p = quad_add(p);
            const float ex = (src[u] >= 0) ? __expf(p * 0.17677669529663689f) : 0.f;
            den += ex;
#pragma unroll
            for (int j = 0; j < 8; ++j) {
                acc[j] = fmaf(ex, bf2f((unsigned short)vS[u][j]), acc[j]);
                sa[j]  = fmaf(ex, ef[j], sa[j]);
            }
        }
#pragma unroll
        for (int u = 0; u < 4; ++u) src[u] = srcN[u];
    }

    // combine the 4 edge groups (once per node)
#pragma unroll
    for (int off = 16; off <= 32; off <<= 1) {
        den += __shfl_xor(den, off, 64);
#pragma unroll
        for (int j = 0; j < 8; ++j) {
            acc[j] += __shfl_xor(acc[j], off, 64);
            sa[j]  += __shfl_xor(sa[j],  off, 64);
        }
    }

    if (grp == 0) {
        const float rden = 1.f / (den + 1e-16f);
        float* so = SB + (size_t)n * D + g * 8;
        unsigned short* po = SAS + (size_t)n * D + g * 8;
#pragma unroll
        for (int j = 0; j < 8; ++j) {
            so[j] = fmaf(acc[j], rden, so[j]);    // + skip (in place)
            po[j] = f2bf(sa[j] * rden);
        }
    }
}

// ---------------------------------------------------------------------------
// fused_mlp: OUT = preout + SAS @ WtCorr; H1 = gelu(OUT@W1+b1);
//            FINAL = OUT + gelu(H1@W2+b2).
// ---------------------------------------------------------------------------
__global__ __launch_bounds__(256) void fused_mlp(
    const float* __restrict__ SB, const unsigned short* __restrict__ SAS,
    const unsigned short* __restrict__ WtC, const unsigned short* __restrict__ Wt1,
    const unsigned short* __restrict__ Wt2,
    const float* __restrict__ b1, const float* __restrict__ b2,
    float* __restrict__ FINAL, int N)
{
    __shared__ unsigned short sw[16384];
    __shared__ unsigned short bounce[64 * 136];
    const int t = threadIdx.x;
    const int lane = t & 63;
    const int w = t >> 6;
    const int row0 = blockIdx.x * 64 + w * 16;
    const int lrow = lane & 15;
    const int kb = (lane >> 4) * 8;
    const int rq = (lane >> 4) * 4;

    ushort8 stg[8];
#pragma unroll
    for (int it = 0; it < 8; ++it)
        stg[it] = *(const ushort8*)(WtC + (t + it * 256) * 8);

    bf16x8 af[4];
    {
        int ar = row0 + lrow; if (ar > N - 1) ar = N - 1;
        const unsigned short* xr = SAS + (size_t)ar * D + kb;
#pragma unroll
        for (int kf = 0; kf < 4; ++kf) af[kf] = *(const bf16x8*)(xr + kf * 32);
    }
    f32x4 out[8];
#pragma unroll
    for (int nf = 0; nf < 8; ++nf) {
        const int col = nf * 16 + lrow;
#pragma unroll
        for (int i = 0; i < 4; ++i) {
            int r = row0 + rq + i;
            out[nf][i] = (r < N) ? SB[(size_t)r * D + col] : 0.f;
        }
    }
#pragma unroll
    for (int it = 0; it < 8; ++it)
        *(ushort8*)(&sw[(t + it * 256) * 8]) = stg[it];
    __syncthreads();

    // GEMM1
#pragma unroll
    for (int nf = 0; nf < 8; ++nf) {
        const int col = nf * 16 + lrow;
#pragma unroll
        for (int kf = 0; kf < 4; ++kf)
            out[nf] = __builtin_amdgcn_mfma_f32_16x16x32_bf16(
                af[kf], ldsB(sw, col, kf * 32 + kb), out[nf], 0, 0, 0);
    }
    __syncthreads();

    // bounce OUT + stage Wt1
#pragma unroll
    for (int it = 0; it < 8; ++it)
        stg[it] = *(const ushort8*)(Wt1 + (t + it * 256) * 8);
#pragma unroll
    for (int nf = 0; nf < 8; ++nf) {
        const int col = nf * 16 + lrow;
#pragma unroll
        for (int i = 0; i < 4; ++i)
            bounce[(w * 16 + rq + i) * 136 + col] = f2bf(out[nf][i]);
    }
#pragma unroll
    for (int it = 0; it < 8; ++it)
        *(ushort8*)(&sw[(t + it * 256) * 8]) = stg[it];
    __syncthreads();

    // GEMM2
    bf16x8 af2[4];
#pragma unroll
    for (int kf = 0; kf < 4; ++kf)
        af2[kf] = *(const bf16x8*)(&bounce[(w * 16 + lrow) * 136 + kb + kf * 32]);
    f32x4 acc2[8];
#pragma unroll
    for (int nf = 0; nf < 8; ++nf) acc2[nf] = (f32x4){0.f, 0.f, 0.f, 0.f};
#pragma unroll
    for (int nf = 0; nf < 8; ++nf) {
        const int col = nf * 16 + lrow;
#pragma unroll
        for (int kf = 0; kf < 4; ++kf)
            acc2[nf] = __builtin_amdgcn_mfma_f32_16x16x32_bf16(
                af2[kf], ldsB(sw, col, kf * 32 + kb), acc2[nf], 0, 0, 0);
    }
    __syncthreads();

    // bounce H1 + stage Wt2
#pragma unroll
    for (int it = 0; it < 8; ++it)
        stg[it] = *(const ushort8*)(Wt2 + (t + it * 256) * 8);
#pragma unroll
    for (int nf = 0; nf < 8; ++nf) {
        const int col = nf * 16 + lrow;
        const float bb = b1[col];
#pragma unroll
        for (int i = 0; i < 4; ++i)
            bounce[(w * 16 + rq + i) * 136 + col] = f2bf(gelu_fast(acc2[nf][i] + bb));
    }
#pragma unroll
    for (int it = 0; it < 8; ++it)
        *(ushort8*)(&sw[(t + it * 256) * 8]) = stg[it];
    __syncthreads();

    // GEMM3 + epilogue
    bf16x8 af3[4];
#pragma unroll
    for (int kf = 0; kf < 4; ++kf)
        af3[kf] = *(const bf16x8*)(&bounce[(w * 16 + lrow) * 136 + kb + kf * 32]);
    f32x4 acc3[8];
#pragma unroll
    for (int nf = 0; nf < 8; ++nf) acc3[nf] = (f32x4){0.f, 0.f, 0.f, 0.f};
#pragma unroll
    for (int nf = 0; nf < 8; ++nf) {
        const int col = nf * 16 + lrow;
#pragma unroll
        for (int kf = 0; kf < 4; ++kf)
            acc3[nf] = __builtin_amdgcn_mfma_f32_16x16x32_bf16(
                af3[kf], ldsB(sw, col, kf * 32 + kb), acc3[nf], 0, 0, 0);
    }
#pragma unroll
    for (int nf = 0; nf < 8; ++nf) {
        const int col = nf * 16 + lrow;
        const float bb = b2[col];
#pragma unroll
        for (int i = 0; i < 4; ++i) {
            int r = row0 + rq + i;
            if (r < N)
                FINAL[(size_t)r * D + col] = out[nf][i] + gelu_fast(acc3[nf][i] + bb);
        }
    }
}

// ---------------------------------------------------------------------------
extern "C" void kernel_launch(void* const* d_in, const int* in_sizes, int n_in,
                              void* d_out, int out_size, void* d_ws, size_t ws_size,
                              hipStream_t stream)
{
    const float* x   = (const float*)d_in[0];
    const int*   EI  = (const int*)  d_in[1];
    const float* EA  = (const float*)d_in[2];
    const float* Wq  = (const float*)d_in[3];
    const float* bq  = (const float*)d_in[4];
    const float* Wk  = (const float*)d_in[5];
    const float* bk  = (const float*)d_in[6];
    const float* Wv  = (const float*)d_in[7];
    const float* bv  = (const float*)d_in[8];
    const float* We  = (const float*)d_in[9];
    const float* Wsk = (const float*)d_in[10];
    const float* bsk = (const float*)d_in[11];
    const float* W1  = (const float*)d_in[12];
    const float* b1  = (const float*)d_in[13];
    const float* W2  = (const float*)d_in[14];
    const float* b2  = (const float*)d_in[15];

    const int N = in_sizes[0] / D;
    const int E = in_sizes[1] / 2;

    char* p = (char*)d_ws;
    auto alloc = [&](size_t bytes) -> void* {
        void* r = (void*)p;
        p += (bytes + 255) & ~(size_t)255;
        return r;
    };
    float*          Sb     = (float*)         alloc((size_t)N * D * 4);   // skip -> preout
    unsigned short* QAb    = (unsigned short*)alloc((size_t)N * 256 * 2); // [Q|QE]
    unsigned short* KVb    = (unsigned short*)alloc((size_t)N * 256 * 2); // [K|V]
    unsigned short* SASb   = (unsigned short*)alloc((size_t)N * D * 2);
    unsigned short* XBb    = (unsigned short*)alloc((size_t)N * D * 2);   // bf16 x
    unsigned short* EAPb   = (unsigned short*)alloc((size_t)E * EDIM * 2);
    int*            srcsb  = (int*)           alloc((size_t)E * 4);
    unsigned short* Wt     = (unsigned short*)alloc((size_t)8 * 16384 * 2);
    float*          bqEb   = (float*)         alloc((size_t)128 * 4);
    int*            deg    = (int*)           alloc((size_t)N * 4);
    int*            rowptr = (int*)           alloc((size_t)(N + 1) * 4);
    int*            cursor = (int*)           alloc((size_t)(N + 1) * 4);
    int*            psums  = (int*)           alloc((size_t)1024 * 4);

    hipMemsetAsync(deg, 0, (size_t)N * sizeof(int), stream);

    const long xtot = (long)N * D;
    const int NB  = (N + 63) / 64;
    const int NB2 = (N + 127) / 128;
    const int EB  = (E + 255) / 256;
    const int XB_ = (int)((xtot + 2047) / 2048);
    const int SB_ = (N + 1023) / 1024;

    prep_kernel<<<513 + EB + XB_, 256, 0, stream>>>(
        Wq, Wk, Wv, Wsk, W1, W2, We, bq, Wt, bqEb, EI, deg, E, EB, x, XBb, xtot);

    scanA<<<SB_, 1024, 0, stream>>>(deg, rowptr, psums, N);
    scanB<<<1, 1024, 0, stream>>>(psums, SB_);
    scanC<<<(N + 255) / 256, 256, 0, stream>>>(rowptr, cursor, psums, N);

    scatter_kernel<<<EB, 256, 0, stream>>>(EI, EA, cursor, srcsb, EAPb, E);

    gemm5<<<5 * NB2, 256, 0, stream>>>(
        XBb, Wt, bq, bk, bv, bsk, bqEb, QAb, KVb, Sb, N, NB2);

    gather_pass<<<(N + 3) / 4, 256, 0, stream>>>(
        rowptr, srcsb, EAPb, QAb, KVb, Sb, SASb, N);

    fused_mlp<<<NB, 256, 0, stream>>>(Sb, SASb,
                                      Wt + (size_t)7 * 16384,
                                      Wt + (size_t)4 * 16384,
                                      Wt + (size_t)5 * 16384,
                                      b1, b2, (float*)d_out, N);
}

// Round 13
// 254.014 us; speedup vs baseline: 1.0214x; 1.0214x over previous
//
#include <hip/hip_runtime.h>
#include <math.h>

// ---------------------------------------------------------------------------
// GraphTransformerBlock: TransformerConv (4 heads x 32) + residual MLP.
// Round 13: gather math -> packed fp16 (v_pk_fma_f16). Q/QE/K/V/EAP stored
// fp16 (no per-element converts in the edge loop, 2 FMA/op). ~2.5x VALU cut.
// Producers (gemm5 epilogue, scatter) emit fp16. MFMA surfaces stay bf16.
// ---------------------------------------------------------------------------

#define D 128
#define EDIM 32

using bf16x8 = __attribute__((ext_vector_type(8))) short;
using f32x4  = __attribute__((ext_vector_type(4))) float;
using ushort8 = __attribute__((ext_vector_type(8))) unsigned short;
using v2h = __attribute__((ext_vector_type(2))) _Float16;

__device__ inline unsigned short f2bf(float f) {
    unsigned int u = __float_as_uint(f);
    u += 0x7FFFu + ((u >> 16) & 1u);          // round-to-nearest-even
    return (unsigned short)(u >> 16);
}
__device__ inline float bf2f(unsigned short h) {
    return __uint_as_float(((unsigned int)h) << 16);
}
__device__ inline unsigned short f2h(float f) {
    union { _Float16 h; unsigned short u; } c;
    c.h = (_Float16)f;
    return c.u;
}
__device__ inline v2h u2h(unsigned int u) {
    union { unsigned int x; v2h h; } c; c.x = u; return c.h;
}
__device__ inline float gelu_fast(float x) {
    float x3 = x * x * x;
    float u = 0.7978845608028654f * (x + 0.044715f * x3);
    float t = 1.f - 2.f / (__expf(2.f * u) + 1.f);   // tanh(u)
    return 0.5f * x * (1.f + t);
}
// sum over aligned 4-lane quad via DPP quad_perm (all 4 lanes get the sum)
__device__ inline float quad_add(float x) {
    int a = __builtin_amdgcn_update_dpp(0, __float_as_int(x), 0xB1, 0xF, 0xF, true);
    x += __int_as_float(a);
    a = __builtin_amdgcn_update_dpp(0, __float_as_int(x), 0x4E, 0xF, 0xF, true);
    x += __int_as_float(a);
    return x;
}

// swizzled B-frag read: element (col, kk0..kk0+7) of the staged weight tile
__device__ inline bf16x8 ldsB(const unsigned short* sw, int col, int kk0) {
    return *(const bf16x8*)(sw + col * 128 + (kk0 ^ ((col & 7) << 3)));
}

// ---------------------------------------------------------------------------
// prep: blocks 0..511 -> 8 pre-swizzled bf16 weight tables
//   m: 0=Wq 1=Wk 2=Wv 3=Wskip 4=W1 5=W2 6=WqE (inline dot) 7=WtCorr
// block 512: bqE.  blocks 513..513+HB-1: hist. blocks 513+HB..: x -> bf16.
// ---------------------------------------------------------------------------
__global__ __launch_bounds__(256) void prep_kernel(
    const float* __restrict__ Wq, const float* __restrict__ Wk,
    const float* __restrict__ Wv, const float* __restrict__ Wsk,
    const float* __restrict__ W1, const float* __restrict__ W2,
    const float* __restrict__ We, const float* __restrict__ bq,
    unsigned short* __restrict__ Wt, float* __restrict__ bqE,
    const int* __restrict__ EI, int* __restrict__ deg, int E, int HB,
    const float* __restrict__ x, unsigned short* __restrict__ XB, long xtot)
{
    if ((int)blockIdx.x >= 513 + HB) {    // x -> bf16 tail
        long i8 = ((long)(blockIdx.x - 513 - HB) * 256 + threadIdx.x) * 8;
        if (i8 + 8 <= xtot) {
            float4 a = *(const float4*)(x + i8);
            float4 b = *(const float4*)(x + i8 + 4);
            ushort8 u;
            u[0] = f2bf(a.x); u[1] = f2bf(a.y); u[2] = f2bf(a.z); u[3] = f2bf(a.w);
            u[4] = f2bf(b.x); u[5] = f2bf(b.y); u[6] = f2bf(b.z); u[7] = f2bf(b.w);
            *(ushort8*)(XB + i8) = u;
        }
        return;
    }
    if (blockIdx.x >= 513) {              // hist
        int e = (blockIdx.x - 513) * 256 + threadIdx.x;
        if (e < E) atomicAdd(&deg[EI[E + e]], 1);
        return;
    }
    int t = blockIdx.x * 256 + threadIdx.x;
    int m = t >> 14;
    int r = t & 16383;
    if (m >= 8) {                         // bqE block
        if (r < 128) {
            const int hb = r & 96, k = r & 31;
            const float* wek = We + (size_t)k * D + hb;
            float s = 0.f;
#pragma unroll 8
            for (int c = 0; c < 32; ++c) s = fmaf(bq[hb + c], wek[c], s);
            bqE[r] = s;
        }
        return;
    }
    int col = r & 127, kk = r >> 7;
    float v;
    if (m < 6) {
        const float* W = (m == 0) ? Wq : (m == 1) ? Wk : (m == 2) ? Wv
                       : (m == 3) ? Wsk : (m == 4) ? W1 : W2;
        v = W[(size_t)kk * D + col];
    } else if (m == 6) {
        const int hb = col & 96;
        const float* wqr = Wq + (size_t)kk * D + hb;
        const float* wer = We + (size_t)(col & 31) * D + hb;
        float s = 0.f;
#pragma unroll 8
        for (int c = 0; c < 32; ++c) s = fmaf(wqr[c], wer[c], s);
        v = s;
    } else {
        v = ((kk >> 5) == (col >> 5)) ? We[(size_t)(kk & 31) * D + col] : 0.f;
    }
    Wt[(size_t)m * 16384 + (size_t)col * 128 + (kk ^ ((col & 7) << 3))] = f2bf(v);
}

// ---------------------------------------------------------------------------
// hierarchical scan
// ---------------------------------------------------------------------------
__global__ __launch_bounds__(1024) void scanA(
    const int* __restrict__ deg, int* __restrict__ rowptr,
    int* __restrict__ psums, int N)
{
    __shared__ int tmp[1024];
    const int t = threadIdx.x;
    const int i = blockIdx.x * 1024 + t;
    int v = (i < N) ? deg[i] : 0;
    tmp[t] = v;
    __syncthreads();
    for (int off = 1; off < 1024; off <<= 1) {
        int add = (t >= off) ? tmp[t - off] : 0;
        __syncthreads();
        tmp[t] += add;
        __syncthreads();
    }
    if (i < N) rowptr[i + 1] = tmp[t];
    if (t == 1023) psums[blockIdx.x] = tmp[1023];
}

__global__ __launch_bounds__(1024) void scanB(int* __restrict__ psums, int nb)
{
    __shared__ int tmp[1024];
    const int t = threadIdx.x;
    int v = (t < nb) ? psums[t] : 0;
    tmp[t] = v;
    __syncthreads();
    for (int off = 1; off < 1024; off <<= 1) {
        int add = (t >= off) ? tmp[t - off] : 0;
        __syncthreads();
        tmp[t] += add;
        __syncthreads();
    }
    if (t < nb) psums[t] = tmp[t] - v;   // exclusive
}

__global__ __launch_bounds__(256) void scanC(
    int* __restrict__ rowptr, int* __restrict__ cursor,
    const int* __restrict__ psums, int N)
{
    int i = blockIdx.x * 256 + threadIdx.x;
    if (i == 0) { rowptr[0] = 0; cursor[0] = 0; }
    if (i < N) {
        int val = rowptr[i + 1] + psums[i >> 10];
        rowptr[i + 1] = val;
        if (i + 1 < N) cursor[i + 1] = val;
    }
}

// ---------------------------------------------------------------------------
// scatter: srcs[pos]=src + EAP[pos]=fp16(edge_attr[e]) (CSR-ordered, 64B row).
// ---------------------------------------------------------------------------
__global__ __launch_bounds__(256) void scatter_kernel(
    const int* __restrict__ EI, const float* __restrict__ EA,
    int* __restrict__ cursor, int* __restrict__ srcs,
    unsigned short* __restrict__ EAP, int E)
{
    int e = blockIdx.x * 256 + threadIdx.x;
    if (e >= E) return;
    int dst = EI[E + e];
    int pos = atomicAdd(&cursor[dst], 1);
    srcs[pos] = EI[e];
    const float4* s4 = (const float4*)(EA + (size_t)e * EDIM);
    unsigned short* op = EAP + (size_t)pos * EDIM;
#pragma unroll
    for (int j = 0; j < 4; ++j) {
        float4 a = s4[2 * j], b = s4[2 * j + 1];
        ushort8 u;
        u[0] = f2h(a.x); u[1] = f2h(a.y); u[2] = f2h(a.z); u[3] = f2h(a.w);
        u[4] = f2h(b.x); u[5] = f2h(b.y); u[6] = f2h(b.z); u[7] = f2h(b.w);
        *(ushort8*)(op + j * 8) = u;
    }
}

// ---------------------------------------------------------------------------
// gemm5: blockIdx.x = m*NB2 + bx, m=0..4 (Q,K,V,skip,QE). 128-row tiles.
// bf16-input MFMA; outputs: Q/K/V/QE stored FP16 (for gather), skip f32.
// fp16 outputs transposed through LDS -> full-line ushort8 stores.
// ---------------------------------------------------------------------------
__global__ __launch_bounds__(256) void gemm5(
    const unsigned short* __restrict__ XB, const unsigned short* __restrict__ Wt,
    const float* __restrict__ bq, const float* __restrict__ bk,
    const float* __restrict__ bv, const float* __restrict__ bs,
    const float* __restrict__ bqE,
    unsigned short* __restrict__ QA, unsigned short* __restrict__ KV,
    float* __restrict__ S, int N, int NB2)
{
    __shared__ unsigned short sw[16384];
    const int t = threadIdx.x;
    const int bid = blockIdx.x;
    const int m = bid / NB2;
    const int bx = bid - m * NB2;
    const int widx = (m < 4) ? m : 6;
    const int lane = t & 63;
    const int w = t >> 6;
    const int row0 = bx * 128 + w * 32;
    const int lrow = lane & 15;
    const int kb = (lane >> 4) * 8;
    const int rq = (lane >> 4) * 4;

    const unsigned short* gsrc = Wt + (size_t)widx * 16384;
    ushort8 stg[8];
#pragma unroll
    for (int it = 0; it < 8; ++it)
        stg[it] = *(const ushort8*)(gsrc + (t + it * 256) * 8);

    bf16x8 af0[4], af1[4];
    {
        int a0 = row0 + lrow;      if (a0 > N - 1) a0 = N - 1;
        int a1 = row0 + 16 + lrow; if (a1 > N - 1) a1 = N - 1;
        const unsigned short* x0 = XB + (size_t)a0 * D + kb;
        const unsigned short* x1 = XB + (size_t)a1 * D + kb;
#pragma unroll
        for (int kf = 0; kf < 4; ++kf) {
            af0[kf] = *(const bf16x8*)(x0 + kf * 32);
            af1[kf] = *(const bf16x8*)(x1 + kf * 32);
        }
    }

#pragma unroll
    for (int it = 0; it < 8; ++it)
        *(ushort8*)(&sw[(t + it * 256) * 8]) = stg[it];
    __syncthreads();

    const float* bias = (m == 0) ? bq : (m == 1) ? bk : (m == 2) ? bv
                      : (m == 3) ? bs : bqE;
    f32x4 acc0[8], acc1[8];
#pragma unroll
    for (int nf = 0; nf < 8; ++nf) {
        acc0[nf] = (f32x4){0.f, 0.f, 0.f, 0.f};
        acc1[nf] = (f32x4){0.f, 0.f, 0.f, 0.f};
    }
#pragma unroll
    for (int nf = 0; nf < 8; ++nf) {
        const int col = nf * 16 + lrow;
#pragma unroll
        for (int kf = 0; kf < 4; ++kf) {
            bf16x8 bfr = ldsB(sw, col, kf * 32 + kb);
            acc0[nf] = __builtin_amdgcn_mfma_f32_16x16x32_bf16(af0[kf], bfr, acc0[nf], 0, 0, 0);
            acc1[nf] = __builtin_amdgcn_mfma_f32_16x16x32_bf16(af1[kf], bfr, acc1[nf], 0, 0, 0);
        }
    }

    if (m == 3) {
        // f32 skip: direct stores (64B-contiguous per (nf,row) segment)
#pragma unroll
        for (int rb = 0; rb < 2; ++rb) {
#pragma unroll
            for (int nf = 0; nf < 8; ++nf) {
                const int col = nf * 16 + lrow;
                const float bb = bias[col];
#pragma unroll
                for (int i = 0; i < 4; ++i) {
                    int r = row0 + rb * 16 + rq + i;
                    if (r < N)
                        S[(size_t)r * D + col] = ((rb == 0) ? acc0[nf][i] : acc1[nf][i]) + bb;
                }
            }
        }
        return;
    }

    // fp16 outputs: bounce through sw (barrier: all MFMA sw-reads are done)
    __syncthreads();
#pragma unroll
    for (int rb = 0; rb < 2; ++rb) {
#pragma unroll
        for (int nf = 0; nf < 8; ++nf) {
            const int col = nf * 16 + lrow;
            const float bb = bias[col];
#pragma unroll
            for (int i = 0; i < 4; ++i)
                sw[(w * 32 + rb * 16 + rq + i) * 128 + col] =
                    f2h(((rb == 0) ? acc0[nf][i] : acc1[nf][i]) + bb);
        }
    }
    // per-wave patch readback (no cross-wave dependency -> no extra barrier)
    unsigned short* gout = (m == 0) ? QA : (m == 1) ? KV
                         : (m == 2) ? KV + 128 : QA + 128;
#pragma unroll
    for (int it = 0; it < 8; ++it) {
        const int gidx = it * 64 + lane;
        const int row_l = gidx >> 4;          // 0..31
        const int chk = gidx & 15;            // 16B chunk within row
        const int r = row0 + row_l;
        ushort8 vv = *(const ushort8*)(&sw[(w * 32 + row_l) * 128 + chk * 8]);
        if (r < N) *(ushort8*)(gout + (size_t)r * 256 + chk * 8) = vv;
    }
}

// ---------------------------------------------------------------------------
// gather: 1 wave per node; 4 edge groups x 16 lanes (lane owns 8 dims),
// 4 edges per group per iteration (16 edges in flight / wave).
// ALL edge math in packed fp16 (v_pk_fma_f16); den/p-combine/exp in f32.
// ---------------------------------------------------------------------------
__global__ __launch_bounds__(256) void gather_pass(
    const int* __restrict__ rowptr, const int* __restrict__ srcs,
    const unsigned short* __restrict__ EAP,
    const unsigned short* __restrict__ QA, const unsigned short* __restrict__ KV,
    float* __restrict__ SB, unsigned short* __restrict__ SAS, int N)
{
    const int lane = threadIdx.x & 63;
    const int wid = threadIdx.x >> 6;
    const int n = blockIdx.x * 4 + wid;
    if (n >= N) return;
    const int g = lane & 15;        // dim slice: d = g*8..+8 (head g>>2)
    const int grp = lane >> 4;      // edge group 0..3
    const int eoff = (g & 3) * 8;   // this lane's EAP slice (halves)

    v2h q2[4], qe2[4];
    {
        uint4 qr  = *(const uint4*)(QA + (size_t)n * 256 + g * 8);
        uint4 qer = *(const uint4*)(QA + (size_t)n * 256 + 128 + g * 8);
        q2[0] = u2h(qr.x);  q2[1] = u2h(qr.y);  q2[2] = u2h(qr.z);  q2[3] = u2h(qr.w);
        qe2[0] = u2h(qer.x); qe2[1] = u2h(qer.y); qe2[2] = u2h(qer.z); qe2[3] = u2h(qer.w);
    }

    const v2h zero2 = {(_Float16)0.f, (_Float16)0.f};
    v2h acc2[4], sa2[4];
#pragma unroll
    for (int i = 0; i < 4; ++i) { acc2[i] = zero2; sa2[i] = zero2; }
    float den = 0.f;

    const int i0 = rowptr[n], i1 = rowptr[n + 1];

    int src[4];
#pragma unroll
    for (int u = 0; u < 4; ++u) {
        int ii = i0 + grp + u * 4;
        src[u] = (ii < i1) ? srcs[ii] : -1;
    }

    for (int base = i0; base < i1; base += 16) {
        // issue all 12 loads for the 4 in-flight edges
        unsigned int kr[4][4], vr[4][4], er[4][4];
#pragma unroll
        for (int u = 0; u < 4; ++u) {
            if (src[u] >= 0) {
                const unsigned short* kv = KV + (size_t)src[u] * 256 + g * 8;
                *(uint4*)kr[u] = *(const uint4*)(kv);
                *(uint4*)vr[u] = *(const uint4*)(kv + 128);
                *(uint4*)er[u] = *(const uint4*)(EAP + (size_t)(base + grp + u * 4) * EDIM + eoff);
            } else {
                *(uint4*)kr[u] = (uint4){0, 0, 0, 0};
                *(uint4*)vr[u] = (uint4){0, 0, 0, 0};
                *(uint4*)er[u] = (uint4){0, 0, 0, 0};
            }
        }
        // prefetch next iteration's src indices
        int srcN[4];
#pragma unroll
        for (int u = 0; u < 4; ++u) {
            int ii = base + 16 + grp + u * 4;
            srcN[u] = (ii < i1) ? srcs[ii] : -1;
        }
        // compute the 4 edges (packed fp16)
#pragma unroll
        for (int u = 0; u < 4; ++u) {
            v2h ps = zero2;
#pragma unroll
            for (int i = 0; i < 4; ++i) {
                ps += q2[i]  * u2h(kr[u][i]);
                ps += qe2[i] * u2h(er[u][i]);
            }
            float p = (float)ps[0] + (float)ps[1];
            p = quad_add(p);                  // 32-dim head dot
            const float ex = (src[u] >= 0) ? __expf(p * 0.17677669529663689f) : 0.f;
            den += ex;
            const _Float16 exh = (_Float16)ex;
            const v2h ex2 = {exh, exh};
#pragma unroll
            for (int i = 0; i < 4; ++i) {
                acc2[i] += ex2 * u2h(vr[u][i]);
                sa2[i]  += ex2 * u2h(er[u][i]);
            }
        }
#pragma unroll
        for (int u = 0; u < 4; ++u) src[u] = srcN[u];
    }

    // to f32, then combine the 4 edge groups (once per node)
    float acc[8], sa[8];
#pragma unroll
    for (int i = 0; i < 4; ++i) {
        acc[2 * i] = (float)acc2[i][0]; acc[2 * i + 1] = (float)acc2[i][1];
        sa[2 * i]  = (float)sa2[i][0];  sa[2 * i + 1]  = (float)sa2[i][1];
    }
#pragma unroll
    for (int off = 16; off <= 32; off <<= 1) {
        den += __shfl_xor(den, off, 64);
#pragma unroll
        for (int j = 0; j < 8; ++j) {
            acc[j] += __shfl_xor(acc[j], off, 64);
            sa[j]  += __shfl_xor(sa[j],  off, 64);
        }
    }

    if (grp == 0) {
        const float rden = 1.f / (den + 1e-16f);
        float* so = SB + (size_t)n * D + g * 8;
        unsigned short* po = SAS + (size_t)n * D + g * 8;
#pragma unroll
        for (int j = 0; j < 8; ++j) {
            so[j] = fmaf(acc[j], rden, so[j]);    // + skip (in place)
            po[j] = f2bf(sa[j] * rden);
        }
    }
}

// ---------------------------------------------------------------------------
// fused_mlp: OUT = preout + SAS @ WtCorr; H1 = gelu(OUT@W1+b1);
//            FINAL = OUT + gelu(H1@W2+b2).
// ---------------------------------------------------------------------------
__global__ __launch_bounds__(256) void fused_mlp(
    const float* __restrict__ SB, const unsigned short* __restrict__ SAS,
    const unsigned short* __restrict__ WtC, const unsigned short* __restrict__ Wt1,
    const unsigned short* __restrict__ Wt2,
    const float* __restrict__ b1, const float* __restrict__ b2,
    float* __restrict__ FINAL, int N)
{
    __shared__ unsigned short sw[16384];
    __shared__ unsigned short bounce[64 * 136];
    const int t = threadIdx.x;
    const int lane = t & 63;
    const int w = t >> 6;
    const int row0 = blockIdx.x * 64 + w * 16;
    const int lrow = lane & 15;
    const int kb = (lane >> 4) * 8;
    const int rq = (lane >> 4) * 4;

    ushort8 stg[8];
#pragma unroll
    for (int it = 0; it < 8; ++it)
        stg[it] = *(const ushort8*)(WtC + (t + it * 256) * 8);

    bf16x8 af[4];
    {
        int ar = row0 + lrow; if (ar > N - 1) ar = N - 1;
        const unsigned short* xr = SAS + (size_t)ar * D + kb;
#pragma unroll
        for (int kf = 0; kf < 4; ++kf) af[kf] = *(const bf16x8*)(xr + kf * 32);
    }
    f32x4 out[8];
#pragma unroll
    for (int nf = 0; nf < 8; ++nf) {
        const int col = nf * 16 + lrow;
#pragma unroll
        for (int i = 0; i < 4; ++i) {
            int r = row0 + rq + i;
            out[nf][i] = (r < N) ? SB[(size_t)r * D + col] : 0.f;
        }
    }
#pragma unroll
    for (int it = 0; it < 8; ++it)
        *(ushort8*)(&sw[(t + it * 256) * 8]) = stg[it];
    __syncthreads();

    // GEMM1
#pragma unroll
    for (int nf = 0; nf < 8; ++nf) {
        const int col = nf * 16 + lrow;
#pragma unroll
        for (int kf = 0; kf < 4; ++kf)
            out[nf] = __builtin_amdgcn_mfma_f32_16x16x32_bf16(
                af[kf], ldsB(sw, col, kf * 32 + kb), out[nf], 0, 0, 0);
    }
    __syncthreads();

    // bounce OUT + stage Wt1
#pragma unroll
    for (int it = 0; it < 8; ++it)
        stg[it] = *(const ushort8*)(Wt1 + (t + it * 256) * 8);
#pragma unroll
    for (int nf = 0; nf < 8; ++nf) {
        const int col = nf * 16 + lrow;
#pragma unroll
        for (int i = 0; i < 4; ++i)
            bounce[(w * 16 + rq + i) * 136 + col] = f2bf(out[nf][i]);
    }
#pragma unroll
    for (int it = 0; it < 8; ++it)
        *(ushort8*)(&sw[(t + it * 256) * 8]) = stg[it];
    __syncthreads();

    // GEMM2
    bf16x8 af2[4];
#pragma unroll
    for (int kf = 0; kf < 4; ++kf)
        af2[kf] = *(const bf16x8*)(&bounce[(w * 16 + lrow) * 136 + kb + kf * 32]);
    f32x4 acc2[8];
#pragma unroll
    for (int nf = 0; nf < 8; ++nf) acc2[nf] = (f32x4){0.f, 0.f, 0.f, 0.f};
#pragma unroll
    for (int nf = 0; nf < 8; ++nf) {
        const int col = nf * 16 + lrow;
#pragma unroll
        for (int kf = 0; kf < 4; ++kf)
            acc2[nf] = __builtin_amdgcn_mfma_f32_16x16x32_bf16(
                af2[kf], ldsB(sw, col, kf * 32 + kb), acc2[nf], 0, 0, 0);
    }
    __syncthreads();

    // bounce H1 + stage Wt2
#pragma unroll
    for (int it = 0; it < 8; ++it)
        stg[it] = *(const ushort8*)(Wt2 + (t + it * 256) * 8);
#pragma unroll
    for (int nf = 0; nf < 8; ++nf) {
        const int col = nf * 16 + lrow;
        const float bb = b1[col];
#pragma unroll
        for (int i = 0; i < 4; ++i)
            bounce[(w * 16 + rq + i) * 136 + col] = f2bf(gelu_fast(acc2[nf][i] + bb));
    }
#pragma unroll
    for (int it = 0; it < 8; ++it)
        *(ushort8*)(&sw[(t + it * 256) * 8]) = stg[it];
    __syncthreads();

    // GEMM3 + epilogue
    bf16x8 af3[4];
#pragma unroll
    for (int kf = 0; kf < 4; ++kf)
        af3[kf] = *(const bf16x8*)(&bounce[(w * 16 + lrow) * 136 + kb + kf * 32]);
    f32x4 acc3[8];
#pragma unroll
    for (int nf = 0; nf < 8; ++nf) acc3[nf] = (f32x4){0.f, 0.f, 0.f, 0.f};
#pragma unroll
    for (int nf = 0; nf < 8; ++nf) {
        const int col = nf * 16 + lrow;
#pragma unroll
        for (int kf = 0; kf < 4; ++kf)
            acc3[nf] = __builtin_amdgcn_mfma_f32_16x16x32_bf16(
                af3[kf], ldsB(sw, col, kf * 32 + kb), acc3[nf], 0, 0, 0);
    }
#pragma unroll
    for (int nf = 0; nf < 8; ++nf) {
        const int col = nf * 16 + lrow;
        const float bb = b2[col];
#pragma unroll
        for (int i = 0; i < 4; ++i) {
            int r = row0 + rq + i;
            if (r < N)
                FINAL[(size_t)r * D + col] = out[nf][i] + gelu_fast(acc3[nf][i] + bb);
        }
    }
}

// ---------------------------------------------------------------------------
extern "C" void kernel_launch(void* const* d_in, const int* in_sizes, int n_in,
                              void* d_out, int out_size, void* d_ws, size_t ws_size,
                              hipStream_t stream)
{
    const float* x   = (const float*)d_in[0];
    const int*   EI  = (const int*)  d_in[1];
    const float* EA  = (const float*)d_in[2];
    const float* Wq  = (const float*)d_in[3];
    const float* bq  = (const float*)d_in[4];
    const float* Wk  = (const float*)d_in[5];
    const float* bk  = (const float*)d_in[6];
    const float* Wv  = (const float*)d_in[7];
    const float* bv  = (const float*)d_in[8];
    const float* We  = (const float*)d_in[9];
    const float* Wsk = (const float*)d_in[10];
    const float* bsk = (const float*)d_in[11];
    const float* W1  = (const float*)d_in[12];
    const float* b1  = (const float*)d_in[13];
    const float* W2  = (const float*)d_in[14];
    const float* b2  = (const float*)d_in[15];

    const int N = in_sizes[0] / D;
    const int E = in_sizes[1] / 2;

    char* p = (char*)d_ws;
    auto alloc = [&](size_t bytes) -> void* {
        void* r = (void*)p;
        p += (bytes + 255) & ~(size_t)255;
        return r;
    };
    float*          Sb     = (float*)         alloc((size_t)N * D * 4);   // skip -> preout
    unsigned short* QAb    = (unsigned short*)alloc((size_t)N * 256 * 2); // [Q|QE] fp16
    unsigned short* KVb    = (unsigned short*)alloc((size_t)N * 256 * 2); // [K|V] fp16
    unsigned short* SASb   = (unsigned short*)alloc((size_t)N * D * 2);   // bf16
    unsigned short* XBb    = (unsigned short*)alloc((size_t)N * D * 2);   // bf16 x
    unsigned short* EAPb   = (unsigned short*)alloc((size_t)E * EDIM * 2);// fp16
    int*            srcsb  = (int*)           alloc((size_t)E * 4);
    unsigned short* Wt     = (unsigned short*)alloc((size_t)8 * 16384 * 2);
    float*          bqEb   = (float*)         alloc((size_t)128 * 4);
    int*            deg    = (int*)           alloc((size_t)N * 4);
    int*            rowptr = (int*)           alloc((size_t)(N + 1) * 4);
    int*            cursor = (int*)           alloc((size_t)(N + 1) * 4);
    int*            psums  = (int*)           alloc((size_t)1024 * 4);

    hipMemsetAsync(deg, 0, (size_t)N * sizeof(int), stream);

    const long xtot = (long)N * D;
    const int NB  = (N + 63) / 64;
    const int NB2 = (N + 127) / 128;
    const int EB  = (E + 255) / 256;
    const int XB_ = (int)((xtot + 2047) / 2048);
    const int SB_ = (N + 1023) / 1024;

    prep_kernel<<<513 + EB + XB_, 256, 0, stream>>>(
        Wq, Wk, Wv, Wsk, W1, W2, We, bq, Wt, bqEb, EI, deg, E, EB, x, XBb, xtot);

    scanA<<<SB_, 1024, 0, stream>>>(deg, rowptr, psums, N);
    scanB<<<1, 1024, 0, stream>>>(psums, SB_);
    scanC<<<(N + 255) / 256, 256, 0, stream>>>(rowptr, cursor, psums, N);

    scatter_kernel<<<EB, 256, 0, stream>>>(EI, EA, cursor, srcsb, EAPb, E);

    gemm5<<<5 * NB2, 256, 0, stream>>>(
        XBb, Wt, bq, bk, bv, bsk, bqEb, QAb, KVb, Sb, N, NB2);

    gather_pass<<<(N + 3) / 4, 256, 0, stream>>>(
        rowptr, srcsb, EAPb, QAb, KVb, Sb, SASb, N);

    fused_mlp<<<NB, 256, 0, stream>>>(Sb, SASb,
                                      Wt + (size_t)7 * 16384,
                                      Wt + (size_t)4 * 16384,
                                      Wt + (size_t)5 * 16384,
                                      b1, b2, (float*)d_out, N);
}